// Round 1
// baseline (254.615 us; speedup 1.0000x reference)
//
#include <hip/hip_runtime.h>
#include <math.h>

#define D 64
#define KC 1024
#define NPIX 65536          // 16*64*64
#define ZQ_ELEMS 4194304    // 16*64*64*64
#define EPS_GAP 0.0625f

// Output layout (fp32, concatenated): [0, 4194304) z_q_st ; [4194304] vq_loss ;
// [4194305, 4259841) indices (as float)

// ws layout (bytes):
//   [0,4096)       float enorm[1024]
//   [4096,5120)    float partials[256]
//   [8192,8196)    int   risky_cnt
//   [8448,270592)  int   risky[65536]

__global__ __launch_bounds__(256) void vq_norms(const float* __restrict__ emb,
                                                float* __restrict__ enorm) {
    int k = blockIdx.x * 256 + threadIdx.x;   // grid 4 * 256 = 1024
    const float4* e4 = (const float4*)(emb + k * D);
    float s = 0.f;
#pragma unroll
    for (int j = 0; j < 16; ++j) {
        float4 v = e4[j];
        s += v.x * v.x + v.y * v.y;
        s += v.z * v.z + v.w * v.w;
    }
    enorm[k] = s;
}

// One thread = (pixel, 256-code range). Block 256 = 64 pixels x 4 ranges.
__global__ __launch_bounds__(256) void vq_scan(
        const float* __restrict__ z_e, const float* __restrict__ emb,
        const float* __restrict__ enorm, float* __restrict__ out,
        int* __restrict__ risky_cnt, int* __restrict__ risky) {
    const int lane = threadIdx.x & 63;
    const int r = __builtin_amdgcn_readfirstlane(threadIdx.x >> 6);  // wave-uniform range id
    const int pix = blockIdx.x * 64 + lane;
    const int w = pix & 63, hh = (pix >> 6) & 63, b = pix >> 12;
    const float* zb = z_e + (((b * 64) * 64 + hh) * 64 + w);

    float f[D];
#pragma unroll
    for (int i = 0; i < D; ++i) f[i] = zb[i * 4096];

    float b1 = INFINITY, b2 = INFINITY;
    int k1 = 0;
    const int k0 = r * 256;
    for (int k = k0; k < k0 + 256; ++k) {
        const float* e = emb + k * D;    // wave-uniform address -> s_load
        float a0 = 0.f, a1 = 0.f, a2 = 0.f, a3 = 0.f;
#pragma unroll
        for (int i = 0; i < D; i += 4) {
            a0 = fmaf(f[i + 0], e[i + 0], a0);
            a1 = fmaf(f[i + 1], e[i + 1], a1);
            a2 = fmaf(f[i + 2], e[i + 2], a2);
            a3 = fmaf(f[i + 3], e[i + 3], a3);
        }
        float dot = (a0 + a1) + (a2 + a3);
        float dist = enorm[k] - 2.0f * dot;   // ||f||^2 const per pixel, irrelevant to argmin
        if (dist < b1) { b2 = b1; b1 = dist; k1 = k; }
        else if (dist < b2) { b2 = dist; }
    }

    __shared__ float sv1[4][64];
    __shared__ float sv2[4][64];
    __shared__ int   si1[4][64];
    sv1[r][lane] = b1; sv2[r][lane] = b2; si1[r][lane] = k1;
    __syncthreads();
    if (r == 0) {
#pragma unroll
        for (int j = 1; j < 4; ++j) {      // ascending ranges: strict < keeps lowest index
            float v1 = sv1[j][lane], v2 = sv2[j][lane];
            int kj = si1[j][lane];
            if (v1 < b1) { b2 = fminf(b1, v2); b1 = v1; k1 = kj; }
            else         { b2 = fminf(b2, v1); }
        }
        out[ZQ_ELEMS + 1 + pix] = (float)k1;
        if (b2 - b1 < EPS_GAP) {           // near-tie: queue for exact fp64 rescore
            int pos = atomicAdd(risky_cnt, 1);
            risky[pos] = pix;
        }
    }
}

// Exact fp64 rescore of near-tie pixels. One wave per pixel, grid-stride.
__global__ __launch_bounds__(256) void vq_rescore(
        const float* __restrict__ z_e, const float* __restrict__ emb,
        float* __restrict__ out, const int* __restrict__ risky_cnt,
        const int* __restrict__ risky) {
    const int lane = threadIdx.x & 63;
    const int wid = (blockIdx.x * 256 + threadIdx.x) >> 6;
    const int nw = (gridDim.x * 256) >> 6;
    const int n = *risky_cnt;
    for (int item = wid; item < n; item += nw) {
        const int pix = risky[item];
        const int w = pix & 63, hh = (pix >> 6) & 63, b = pix >> 12;
        const float* zb = z_e + (((b * 64) * 64 + hh) * 64 + w);
        float f[D];
#pragma unroll
        for (int i = 0; i < D; ++i) f[i] = zb[i * 4096];
        double best = INFINITY;
        int bk = KC;
        for (int j = 0; j < KC / 64; ++j) {
            const int k = j * 64 + lane;
            const float* e = emb + k * D;
            double acc = 0.0;
#pragma unroll
            for (int i = 0; i < D; ++i) {
                double dd = (double)f[i] - (double)e[i];
                acc = fma(dd, dd, acc);
            }
            if (acc < best || (acc == best && k < bk)) { best = acc; bk = k; }
        }
        for (int off = 32; off; off >>= 1) {
            double ov = __shfl_down(best, off, 64);
            int oi = __shfl_down(bk, off, 64);
            if (ov < best || (ov == best && oi < bk)) { best = ov; bk = oi; }
        }
        if (lane == 0) out[ZQ_ELEMS + 1 + pix] = (float)bk;
    }
}

// Gather selected rows, write z_q (B,D,H,W), accumulate per-block loss partials.
__global__ __launch_bounds__(256) void vq_gather(
        const float* __restrict__ z_e, const float* __restrict__ emb,
        float* __restrict__ out, float* __restrict__ partials) {
    const int pix = blockIdx.x * 256 + threadIdx.x;   // grid 256
    const int w = pix & 63, hh = (pix >> 6) & 63, b = pix >> 12;
    const float* zb = z_e + (((b * 64) * 64 + hh) * 64 + w);
    float* ob = out + (((b * 64) * 64 + hh) * 64 + w);
    const int k = (int)out[ZQ_ELEMS + 1 + pix];
    const float4* e4 = (const float4*)(emb + k * D);
    float ss = 0.f;
#pragma unroll
    for (int j = 0; j < 16; ++j) {
        float4 q = e4[j];
        float z0 = zb[(4 * j + 0) * 4096], z1 = zb[(4 * j + 1) * 4096];
        float z2 = zb[(4 * j + 2) * 4096], z3 = zb[(4 * j + 3) * 4096];
        ob[(4 * j + 0) * 4096] = q.x; ob[(4 * j + 1) * 4096] = q.y;
        ob[(4 * j + 2) * 4096] = q.z; ob[(4 * j + 3) * 4096] = q.w;
        float d0 = q.x - z0, d1 = q.y - z1, d2 = q.z - z2, d3 = q.w - z3;
        ss += d0 * d0 + d1 * d1 + d2 * d2 + d3 * d3;
    }
    for (int off = 32; off; off >>= 1) ss += __shfl_down(ss, off, 64);
    __shared__ float sred[4];
    if ((threadIdx.x & 63) == 0) sred[threadIdx.x >> 6] = ss;
    __syncthreads();
    if (threadIdx.x == 0)
        partials[blockIdx.x] = (sred[0] + sred[1]) + (sred[2] + sred[3]);
}

__global__ __launch_bounds__(256) void vq_finalize(const float* __restrict__ partials,
                                                   float* __restrict__ out) {
    float acc = partials[threadIdx.x];
    for (int off = 32; off; off >>= 1) acc += __shfl_down(acc, off, 64);
    __shared__ float sred[4];
    if ((threadIdx.x & 63) == 0) sred[threadIdx.x >> 6] = acc;
    __syncthreads();
    if (threadIdx.x == 0)
        out[ZQ_ELEMS] = ((sred[0] + sred[1]) + (sred[2] + sred[3])) *
                        (1.25f / (float)ZQ_ELEMS);   // codebook + BETA*commit = 1.25*mse
}

extern "C" void kernel_launch(void* const* d_in, const int* in_sizes, int n_in,
                              void* d_out, int out_size, void* d_ws, size_t ws_size,
                              hipStream_t stream) {
    const float* z_e = (const float*)d_in[0];
    const float* emb = (const float*)d_in[1];
    float* out = (float*)d_out;
    char* ws = (char*)d_ws;
    float* enorm    = (float*)ws;
    float* partials = (float*)(ws + 4096);
    int*   risky_cnt = (int*)(ws + 8192);
    int*   risky     = (int*)(ws + 8448);

    hipMemsetAsync(risky_cnt, 0, 4, stream);
    vq_norms<<<4, 256, 0, stream>>>(emb, enorm);
    vq_scan<<<1024, 256, 0, stream>>>(z_e, emb, enorm, out, risky_cnt, risky);
    vq_rescore<<<256, 256, 0, stream>>>(z_e, emb, out, risky_cnt, risky);
    vq_gather<<<256, 256, 0, stream>>>(z_e, emb, out, partials);
    vq_finalize<<<1, 256, 0, stream>>>(partials, out);
}

// Round 2
// 199.536 us; speedup vs baseline: 1.2760x; 1.2760x over previous
//
#include <hip/hip_runtime.h>
#include <math.h>

typedef short  short8 __attribute__((ext_vector_type(8)));
typedef float  f32x4  __attribute__((ext_vector_type(4)));

#define ZQ_ELEMS 4194304    // 16*64*64*64
#define NPIX     65536
#define KC       1024
#define RISK_FLAG 65536.0f
#define EPS_HALF  0.005f    // gap threshold in (dot - ||e||^2/2) units; dist gap = 2x

// Output layout (fp32, concat): [0,4194304) z_q_st ; [4194304] vq_loss ;
// [4194305, 4259841) indices (as float)
//
// ws layout (bytes):
//   [0,131072)        ushort emb_hi[65536]   (dead after vq_scan)
//   [131072,262144)   ushort emb_lo[65536]   (dead after vq_scan)
//   [262144,266240)   float  enorm[1024]
//   [0,1024)          float  partials[256]   (gather phase; overlaps dead emb_hi)

__device__ inline unsigned short bf16_rne(float f) {
    union { float fv; unsigned u; } a; a.fv = f;
    unsigned r = a.u + 0x7FFFu + ((a.u >> 16) & 1u);
    return (unsigned short)(r >> 16);
}
__device__ inline float bf16_to_f(unsigned short h) {
    union { unsigned u; float fv; } a; a.u = ((unsigned)h) << 16;
    return a.fv;
}

__global__ __launch_bounds__(256) void vq_prep(const float* __restrict__ emb,
        unsigned short* __restrict__ ehi, unsigned short* __restrict__ elo,
        float* __restrict__ enorm) {
    const int k = blockIdx.x * 256 + threadIdx.x;   // grid 4
    const float4* e4 = (const float4*)(emb + k * 64);
    float s = 0.f;
#pragma unroll
    for (int j = 0; j < 16; ++j) {
        float4 v = e4[j];
        float vv[4] = {v.x, v.y, v.z, v.w};
        ushort4 hv, lv;
        unsigned short h[4], l[4];
#pragma unroll
        for (int t = 0; t < 4; ++t) {
            s = fmaf(vv[t], vv[t], s);
            h[t] = bf16_rne(vv[t]);
            l[t] = bf16_rne(vv[t] - bf16_to_f(h[t]));
        }
        hv.x = h[0]; hv.y = h[1]; hv.z = h[2]; hv.w = h[3];
        lv.x = l[0]; lv.y = l[1]; lv.z = l[2]; lv.w = l[3];
        *(ushort4*)(ehi + k * 64 + j * 4) = hv;
        *(ushort4*)(elo + k * 64 + j * 4) = lv;
    }
    enorm[k] = s;
}

// One wave = 16 pixels x all 1024 codes via MFMA. Block 256 = 4 waves, grid 1024.
__global__ __launch_bounds__(256) void vq_scan(const float* __restrict__ z_e,
        const unsigned short* __restrict__ ehi, const unsigned short* __restrict__ elo,
        const float* __restrict__ enorm, float* __restrict__ out) {
    const int lane = threadIdx.x & 63;
    const int g    = lane >> 4;           // k-group within fragment
    const int col  = lane & 15;           // A-row (pixel) / B-col (code) slot
    const int base = blockIdx.x * 64 + (threadIdx.x >> 6) * 16;

    // ---- A fragments: pixel = base+col, dims k = g*8+j (chunk0) / 32+g*8+j (chunk1)
    short8 fh0, fh1, fl0, fl1;
    {
        const int p = base + col;
        const float* zb = z_e + (p >> 12) * 262144 + (p & 4095);
#pragma unroll
        for (int j = 0; j < 8; ++j) {
            float v0 = zb[(g * 8 + j) * 4096];
            float v1 = zb[(32 + g * 8 + j) * 4096];
            unsigned short h0 = bf16_rne(v0);
            unsigned short h1 = bf16_rne(v1);
            fh0[j] = (short)h0; fl0[j] = (short)bf16_rne(v0 - bf16_to_f(h0));
            fh1[j] = (short)h1; fl1[j] = (short)bf16_rne(v1 - bf16_to_f(h1));
        }
    }

    float b1[4], b2[4]; int k1[4];
#pragma unroll
    for (int r = 0; r < 4; ++r) { b1[r] = -INFINITY; b2[r] = -INFINITY; k1[r] = 0; }

    for (int c = 0; c < 64; ++c) {
        const int code = c * 16 + col;
        const unsigned short* ph = ehi + code * 64 + g * 8;
        const unsigned short* pl = elo + code * 64 + g * 8;
        short8 eh0 = *(const short8*)ph;
        short8 eh1 = *(const short8*)(ph + 32);
        short8 el0 = *(const short8*)pl;
        short8 el1 = *(const short8*)(pl + 32);
        float en = enorm[code];
        f32x4 acc = { -0.5f * en, -0.5f * en, -0.5f * en, -0.5f * en };
        acc = __builtin_amdgcn_mfma_f32_16x16x32_bf16(fh0, eh0, acc, 0, 0, 0);
        acc = __builtin_amdgcn_mfma_f32_16x16x32_bf16(fh1, eh1, acc, 0, 0, 0);
        acc = __builtin_amdgcn_mfma_f32_16x16x32_bf16(fl0, eh0, acc, 0, 0, 0);
        acc = __builtin_amdgcn_mfma_f32_16x16x32_bf16(fl1, eh1, acc, 0, 0, 0);
        acc = __builtin_amdgcn_mfma_f32_16x16x32_bf16(fh0, el0, acc, 0, 0, 0);
        acc = __builtin_amdgcn_mfma_f32_16x16x32_bf16(fh1, el1, acc, 0, 0, 0);
#pragma unroll
        for (int r = 0; r < 4; ++r) {
            float v = acc[r];
            bool better = v > b1[r];
            b2[r] = better ? b1[r] : fmaxf(b2[r], v);
            k1[r] = better ? code : k1[r];
            b1[r] = fmaxf(b1[r], v);
        }
    }

    // cross-lane reduce over the 16 code-slots (lanes sharing g have same pixel rows)
#pragma unroll
    for (int s = 1; s < 16; s <<= 1) {
#pragma unroll
        for (int r = 0; r < 4; ++r) {
            float o1 = __shfl_xor(b1[r], s, 64);
            float o2 = __shfl_xor(b2[r], s, 64);
            int   oi = __shfl_xor(k1[r], s, 64);
            bool take = (o1 > b1[r]) || (o1 == b1[r] && oi < k1[r]);
            float nb2 = fmaxf(fminf(b1[r], o1), fmaxf(b2[r], o2));
            b1[r] = take ? o1 : b1[r];
            k1[r] = take ? oi : k1[r];
            b2[r] = nb2;
        }
    }
    if (col == 0) {
#pragma unroll
        for (int r = 0; r < 4; ++r) {
            const int pix = base + g * 4 + r;   // C/D row = (lane>>4)*4 + reg
            float flag = (b1[r] - b2[r] < EPS_HALF) ? RISK_FLAG : 0.0f;
            out[ZQ_ELEMS + 1 + pix] = (float)k1[r] + flag;
        }
    }
}

// Exact fp64 rescore of flagged pixels (index value >= RISK_FLAG). Grid 64.
__global__ __launch_bounds__(256) void vq_rescore(const float* __restrict__ z_e,
        const float* __restrict__ emb, float* __restrict__ out) {
    const int lane = threadIdx.x & 63;
    const int wid  = (blockIdx.x * 256 + threadIdx.x) >> 6;   // 256 waves
    float* idxp = out + ZQ_ELEMS + 1;
    for (int t = 0; t < 4; ++t) {
        const int pbase = wid * 256 + t * 64;
        float v = idxp[pbase + lane];
        unsigned long long m = __ballot(v >= RISK_FLAG);
        while (m) {
            const int i = __builtin_ctzll(m);
            m &= m - 1;
            const int pix = pbase + i;
            const float* zb = z_e + (pix >> 12) * 262144 + (pix & 4095);
            float f[64];
#pragma unroll
            for (int d = 0; d < 64; ++d) f[d] = zb[d * 4096];
            double best = INFINITY; int bk = KC;
            for (int j = 0; j < 16; ++j) {
                const int k = j * 64 + lane;
                const float* e = emb + k * 64;
                double a0 = 0.0, a1 = 0.0;
#pragma unroll
                for (int d = 0; d < 64; d += 2) {
                    double d0 = (double)f[d]     - (double)e[d];
                    double d1 = (double)f[d + 1] - (double)e[d + 1];
                    a0 = fma(d0, d0, a0);
                    a1 = fma(d1, d1, a1);
                }
                double acc = a0 + a1;
                if (acc < best || (acc == best && k < bk)) { best = acc; bk = k; }
            }
            for (int off = 32; off; off >>= 1) {
                double ov = __shfl_down(best, off, 64);
                int    oi = __shfl_down(bk, off, 64);
                if (ov < best || (ov == best && oi < bk)) { best = ov; bk = oi; }
            }
            if (lane == 0) idxp[pix] = (float)bk;
        }
    }
}

// Gather selected rows, write z_q (B,D,H,W), per-block loss partials. Grid 256.
__global__ __launch_bounds__(256) void vq_gather(
        const float* __restrict__ z_e, const float* __restrict__ emb,
        float* __restrict__ out, float* __restrict__ partials) {
    const int pix = blockIdx.x * 256 + threadIdx.x;
    const float* zb = z_e + (pix >> 12) * 262144 + (pix & 4095);
    float* ob = out + (pix >> 12) * 262144 + (pix & 4095);
    const int k = (int)out[ZQ_ELEMS + 1 + pix];
    const float4* e4 = (const float4*)(emb + k * 64);
    float ss = 0.f;
#pragma unroll
    for (int j = 0; j < 16; ++j) {
        float4 q = e4[j];
        float z0 = zb[(4 * j + 0) * 4096], z1 = zb[(4 * j + 1) * 4096];
        float z2 = zb[(4 * j + 2) * 4096], z3 = zb[(4 * j + 3) * 4096];
        ob[(4 * j + 0) * 4096] = q.x; ob[(4 * j + 1) * 4096] = q.y;
        ob[(4 * j + 2) * 4096] = q.z; ob[(4 * j + 3) * 4096] = q.w;
        float d0 = q.x - z0, d1 = q.y - z1, d2 = q.z - z2, d3 = q.w - z3;
        ss += d0 * d0 + d1 * d1 + d2 * d2 + d3 * d3;
    }
    for (int off = 32; off; off >>= 1) ss += __shfl_down(ss, off, 64);
    __shared__ float sred[4];
    if ((threadIdx.x & 63) == 0) sred[threadIdx.x >> 6] = ss;
    __syncthreads();
    if (threadIdx.x == 0)
        partials[blockIdx.x] = (sred[0] + sred[1]) + (sred[2] + sred[3]);
}

__global__ __launch_bounds__(256) void vq_finalize(const float* __restrict__ partials,
                                                   float* __restrict__ out) {
    float acc = partials[threadIdx.x];
    for (int off = 32; off; off >>= 1) acc += __shfl_down(acc, off, 64);
    __shared__ float sred[4];
    if ((threadIdx.x & 63) == 0) sred[threadIdx.x >> 6] = acc;
    __syncthreads();
    if (threadIdx.x == 0)
        out[ZQ_ELEMS] = ((sred[0] + sred[1]) + (sred[2] + sred[3])) *
                        (1.25f / (float)ZQ_ELEMS);
}

extern "C" void kernel_launch(void* const* d_in, const int* in_sizes, int n_in,
                              void* d_out, int out_size, void* d_ws, size_t ws_size,
                              hipStream_t stream) {
    const float* z_e = (const float*)d_in[0];
    const float* emb = (const float*)d_in[1];
    float* out = (float*)d_out;
    char* ws = (char*)d_ws;
    unsigned short* ehi = (unsigned short*)ws;
    unsigned short* elo = (unsigned short*)(ws + 131072);
    float* enorm    = (float*)(ws + 262144);
    float* partials = (float*)ws;   // overlaps ehi (dead by gather time)

    vq_prep<<<4, 256, 0, stream>>>(emb, ehi, elo, enorm);
    vq_scan<<<1024, 256, 0, stream>>>(z_e, ehi, elo, enorm, out);
    vq_rescore<<<64, 256, 0, stream>>>(z_e, emb, out);
    vq_gather<<<256, 256, 0, stream>>>(z_e, emb, out, partials);
    vq_finalize<<<1, 256, 0, stream>>>(partials, out);
}

// Round 3
// 128.547 us; speedup vs baseline: 1.9807x; 1.5522x over previous
//
#include <hip/hip_runtime.h>
#include <math.h>

typedef short  short8 __attribute__((ext_vector_type(8)));
typedef float  f32x4  __attribute__((ext_vector_type(4)));

#define ZQ_ELEMS 4194304    // 16*64*64*64
#define NPIX     65536
#define KC       1024
#define RISK_FLAG 65536.0f
#define EPS_HALF  0.005f

// Output layout (fp32, concat): [0,4194304) z_q_st ; [4194304] vq_loss ;
// [4194305, 4259841) indices (as float)
//
// ws layout (bytes):
//   [0,131072)        ushort emb_hi[65536]     (dead after vq_scan)
//   [131072,262144)   ushort emb_lo[65536]     (dead after vq_scan)
//   [262144,266240)   float  enorm[1024]
//   [131072,147456)   float  partials[4096]    (gather; overlaps dead emb_lo)

__device__ inline unsigned short bf16_rne(float f) {
    union { float fv; unsigned u; } a; a.fv = f;
    unsigned r = a.u + 0x7FFFu + ((a.u >> 16) & 1u);
    return (unsigned short)(r >> 16);
}
__device__ inline float bf16_to_f(unsigned short h) {
    union { unsigned u; float fv; } a; a.u = ((unsigned)h) << 16;
    return a.fv;
}

__global__ __launch_bounds__(256) void vq_prep(const float* __restrict__ emb,
        unsigned short* __restrict__ ehi, unsigned short* __restrict__ elo,
        float* __restrict__ enorm) {
    const int k = blockIdx.x * 256 + threadIdx.x;   // grid 4
    const float4* e4 = (const float4*)(emb + k * 64);
    float s = 0.f;
#pragma unroll
    for (int j = 0; j < 16; ++j) {
        float4 v = e4[j];
        float vv[4] = {v.x, v.y, v.z, v.w};
        ushort4 hv, lv;
        unsigned short h[4], l[4];
#pragma unroll
        for (int t = 0; t < 4; ++t) {
            s = fmaf(vv[t], vv[t], s);
            h[t] = bf16_rne(vv[t]);
            l[t] = bf16_rne(vv[t] - bf16_to_f(h[t]));
        }
        hv.x = h[0]; hv.y = h[1]; hv.z = h[2]; hv.w = h[3];
        lv.x = l[0]; lv.y = l[1]; lv.z = l[2]; lv.w = l[3];
        *(ushort4*)(ehi + k * 64 + j * 4) = hv;
        *(ushort4*)(elo + k * 64 + j * 4) = lv;
    }
    enorm[k] = s;
}

// Block 256 = 4 waves = 2 pixel-supergroups(64 pix) x 2 code-halves(512 codes).
// Each wave: 4 A-tiles x 32 c-iters x 6 MFMA = 768 MFMA. Grid 512.
#define LOADB(c, EH0, EH1, EL0, EL1, EN) {                    \
    const int code_ = chbase + (c) * 16 + col;                \
    const unsigned short* ph_ = ehi + code_ * 64 + g * 8;     \
    const unsigned short* pl_ = elo + code_ * 64 + g * 8;     \
    EH0 = *(const short8*)ph_;  EH1 = *(const short8*)(ph_ + 32); \
    EL0 = *(const short8*)pl_;  EL1 = *(const short8*)(pl_ + 32); \
    EN  = enorm[code_]; }

__global__ __launch_bounds__(256, 2) void vq_scan(const float* __restrict__ z_e,
        const unsigned short* __restrict__ ehi, const unsigned short* __restrict__ elo,
        const float* __restrict__ enorm, float* __restrict__ out) {
    const int lane = threadIdx.x & 63;
    const int col  = lane & 15;
    const int g    = lane >> 4;
    const int wv   = threadIdx.x >> 6;
    const int pg   = wv >> 1;               // pixel supergroup (0/1)
    const int ch   = wv & 1;                // code half (0/1)
    const int pbase = blockIdx.x * 128 + pg * 64;
    const int chbase = ch * 512;

    // ---- A fragments: 4 tiles of 16 pixels, hi/lo split, 2 k-chunks
    short8 fh[4][2], fl[4][2];
#pragma unroll
    for (int q = 0; q < 4; ++q) {
        const int p = pbase + q * 16 + col;
        const float* zb = z_e + (p >> 12) * 262144 + (p & 4095);
#pragma unroll
        for (int j = 0; j < 8; ++j) {
            float v0 = zb[(g * 8 + j) * 4096];
            float v1 = zb[(32 + g * 8 + j) * 4096];
            unsigned short h0 = bf16_rne(v0);
            unsigned short h1 = bf16_rne(v1);
            fh[q][0][j] = (short)h0; fl[q][0][j] = (short)bf16_rne(v0 - bf16_to_f(h0));
            fh[q][1][j] = (short)h1; fl[q][1][j] = (short)bf16_rne(v1 - bf16_to_f(h1));
        }
    }

    float b1[4][4], b2[4][4]; int k1[4][4];
#pragma unroll
    for (int q = 0; q < 4; ++q)
#pragma unroll
        for (int r = 0; r < 4; ++r) { b1[q][r] = -INFINITY; b2[q][r] = -INFINITY; k1[q][r] = 0; }

    const f32x4 zero4 = {0.f, 0.f, 0.f, 0.f};
    short8 eh0a, eh1a, el0a, el1a; float ena;
    LOADB(0, eh0a, eh1a, el0a, el1a, ena);

#pragma unroll 2
    for (int c = 0; c < 32; ++c) {
        short8 eh0b, eh1b, el0b, el1b; float enb;
        LOADB((c + 1) & 31, eh0b, eh1b, el0b, el1b, enb);
        const int codecur = chbase + c * 16 + col;
#pragma unroll
        for (int q = 0; q < 4; ++q) {
            f32x4 acc;
            acc = __builtin_amdgcn_mfma_f32_16x16x32_bf16(fh[q][0], eh0a, zero4, 0, 0, 0);
            acc = __builtin_amdgcn_mfma_f32_16x16x32_bf16(fh[q][1], eh1a, acc, 0, 0, 0);
            acc = __builtin_amdgcn_mfma_f32_16x16x32_bf16(fl[q][0], eh0a, acc, 0, 0, 0);
            acc = __builtin_amdgcn_mfma_f32_16x16x32_bf16(fl[q][1], eh1a, acc, 0, 0, 0);
            acc = __builtin_amdgcn_mfma_f32_16x16x32_bf16(fh[q][0], el0a, acc, 0, 0, 0);
            acc = __builtin_amdgcn_mfma_f32_16x16x32_bf16(fh[q][1], el1a, acc, 0, 0, 0);
#pragma unroll
            for (int r = 0; r < 4; ++r) {
                float v = fmaf(ena, -0.5f, acc[r]);
                bool better = v > b1[q][r];
                b2[q][r] = better ? b1[q][r] : fmaxf(b2[q][r], v);
                k1[q][r] = better ? codecur : k1[q][r];
                b1[q][r] = fmaxf(b1[q][r], v);
            }
        }
        eh0a = eh0b; eh1a = eh1b; el0a = el0b; el1a = el1b; ena = enb;
    }

    // reduce over the 16 code-slots (xor over low 4 lane bits)
#pragma unroll
    for (int s = 1; s < 16; s <<= 1) {
#pragma unroll
        for (int q = 0; q < 4; ++q)
#pragma unroll
            for (int r = 0; r < 4; ++r) {
                float o1 = __shfl_xor(b1[q][r], s, 64);
                float o2 = __shfl_xor(b2[q][r], s, 64);
                int   oi = __shfl_xor(k1[q][r], s, 64);
                bool take = (o1 > b1[q][r]) || (o1 == b1[q][r] && oi < k1[q][r]);
                float nb2 = fmaxf(fminf(b1[q][r], o1), fmaxf(b2[q][r], o2));
                b1[q][r] = take ? o1 : b1[q][r];
                k1[q][r] = take ? oi : k1[q][r];
                b2[q][r] = nb2;
            }
    }

    // merge the two code-halves via LDS (partner codes all higher -> strict >)
    __shared__ float sb1[2][64];
    __shared__ float sb2[2][64];
    __shared__ int   sk1[2][64];
    if (ch == 1 && col == 0) {
#pragma unroll
        for (int q = 0; q < 4; ++q)
#pragma unroll
            for (int r = 0; r < 4; ++r) {
                const int idx = g * 16 + q * 4 + r;
                sb1[pg][idx] = b1[q][r]; sb2[pg][idx] = b2[q][r]; sk1[pg][idx] = k1[q][r];
            }
    }
    __syncthreads();
    if (ch == 0 && col == 0) {
#pragma unroll
        for (int q = 0; q < 4; ++q)
#pragma unroll
            for (int r = 0; r < 4; ++r) {
                const int idx = g * 16 + q * 4 + r;
                float o1 = sb1[pg][idx], o2 = sb2[pg][idx]; int oi = sk1[pg][idx];
                float nb2 = fmaxf(fminf(b1[q][r], o1), fmaxf(b2[q][r], o2));
                if (o1 > b1[q][r]) { b1[q][r] = o1; k1[q][r] = oi; }
                b2[q][r] = nb2;
                const int pix = pbase + q * 16 + g * 4 + r;
                float flag = (b1[q][r] - b2[q][r] < EPS_HALF) ? RISK_FLAG : 0.0f;
                out[ZQ_ELEMS + 1 + pix] = (float)k1[q][r] + flag;
            }
    }
}

// Exact fp64 rescore of flagged pixels (index value >= RISK_FLAG). Grid 64.
__global__ __launch_bounds__(256) void vq_rescore(const float* __restrict__ z_e,
        const float* __restrict__ emb, float* __restrict__ out) {
    const int lane = threadIdx.x & 63;
    const int wid  = (blockIdx.x * 256 + threadIdx.x) >> 6;   // 256 waves
    float* idxp = out + ZQ_ELEMS + 1;
    for (int t = 0; t < 4; ++t) {
        const int pbase = wid * 256 + t * 64;
        float v = idxp[pbase + lane];
        unsigned long long m = __ballot(v >= RISK_FLAG);
        while (m) {
            const int i = __builtin_ctzll(m);
            m &= m - 1;
            const int pix = pbase + i;
            const float* zb = z_e + (pix >> 12) * 262144 + (pix & 4095);
            float f[64];
#pragma unroll
            for (int d = 0; d < 64; ++d) f[d] = zb[d * 4096];
            double best = INFINITY; int bk = KC;
            for (int j = 0; j < 16; ++j) {
                const int k = j * 64 + lane;
                const float* e = emb + k * 64;
                double a0 = 0.0, a1 = 0.0;
#pragma unroll
                for (int d = 0; d < 64; d += 2) {
                    double d0 = (double)f[d]     - (double)e[d];
                    double d1 = (double)f[d + 1] - (double)e[d + 1];
                    a0 = fma(d0, d0, a0);
                    a1 = fma(d1, d1, a1);
                }
                double acc = a0 + a1;
                if (acc < best || (acc == best && k < bk)) { best = acc; bk = k; }
            }
            for (int off = 32; off; off >>= 1) {
                double ov = __shfl_down(best, off, 64);
                int    oi = __shfl_down(bk, off, 64);
                if (ov < best || (ov == best && oi < bk)) { best = ov; bk = oi; }
            }
            if (lane == 0) idxp[pix] = (float)bk;
        }
    }
}

// Dim-major gather: thread handles 4 consecutive elements of (B,D,H,W). Grid 4096.
__global__ __launch_bounds__(256) void vq_gather(
        const float* __restrict__ z_e, const float* __restrict__ emb,
        float* __restrict__ out, float* __restrict__ partials) {
    const int E = (blockIdx.x * 256 + threadIdx.x) * 4;
    const int b = E >> 18, d = (E >> 12) & 63, hw = E & 4095;
    const int pixbase = (b << 12) + hw;
    const float* idxp = out + ZQ_ELEMS + 1;
    float4 z = *(const float4*)(z_e + E);
    int k0 = (int)idxp[pixbase + 0];
    int k1 = (int)idxp[pixbase + 1];
    int k2 = (int)idxp[pixbase + 2];
    int k3 = (int)idxp[pixbase + 3];
    float4 q;
    q.x = emb[k0 * 64 + d]; q.y = emb[k1 * 64 + d];
    q.z = emb[k2 * 64 + d]; q.w = emb[k3 * 64 + d];
    *(float4*)(out + E) = q;
    float d0 = q.x - z.x, d1 = q.y - z.y, d2 = q.z - z.z, d3 = q.w - z.w;
    float ss = d0 * d0 + d1 * d1 + d2 * d2 + d3 * d3;
    for (int off = 32; off; off >>= 1) ss += __shfl_down(ss, off, 64);
    __shared__ float sred[4];
    if ((threadIdx.x & 63) == 0) sred[threadIdx.x >> 6] = ss;
    __syncthreads();
    if (threadIdx.x == 0)
        partials[blockIdx.x] = (sred[0] + sred[1]) + (sred[2] + sred[3]);
}

__global__ __launch_bounds__(256) void vq_finalize(const float* __restrict__ partials,
                                                   float* __restrict__ out) {
    float acc = 0.f;
#pragma unroll
    for (int i = 0; i < 16; ++i) acc += partials[threadIdx.x * 16 + i];
    for (int off = 32; off; off >>= 1) acc += __shfl_down(acc, off, 64);
    __shared__ float sred[4];
    if ((threadIdx.x & 63) == 0) sred[threadIdx.x >> 6] = acc;
    __syncthreads();
    if (threadIdx.x == 0)
        out[ZQ_ELEMS] = ((sred[0] + sred[1]) + (sred[2] + sred[3])) *
                        (1.25f / (float)ZQ_ELEMS);
}

extern "C" void kernel_launch(void* const* d_in, const int* in_sizes, int n_in,
                              void* d_out, int out_size, void* d_ws, size_t ws_size,
                              hipStream_t stream) {
    const float* z_e = (const float*)d_in[0];
    const float* emb = (const float*)d_in[1];
    float* out = (float*)d_out;
    char* ws = (char*)d_ws;
    unsigned short* ehi = (unsigned short*)ws;
    unsigned short* elo = (unsigned short*)(ws + 131072);
    float* enorm    = (float*)(ws + 262144);
    float* partials = (float*)(ws + 131072);   // overlaps elo (dead by gather time)

    vq_prep<<<4, 256, 0, stream>>>(emb, ehi, elo, enorm);
    vq_scan<<<512, 256, 0, stream>>>(z_e, ehi, elo, enorm, out);
    vq_rescore<<<64, 256, 0, stream>>>(z_e, emb, out);
    vq_gather<<<4096, 256, 0, stream>>>(z_e, emb, out, partials);
    vq_finalize<<<1, 256, 0, stream>>>(partials, out);
}

// Round 4
// 111.811 us; speedup vs baseline: 2.2772x; 1.1497x over previous
//
#include <hip/hip_runtime.h>
#include <math.h>

typedef short  short8 __attribute__((ext_vector_type(8)));
typedef float  f32x4  __attribute__((ext_vector_type(4)));

#define ZQ_ELEMS 4194304    // 16*64*64*64
#define NPIX     65536
#define KC       1024
#define RISK_FLAG 65536.0f
#define EPS_HALF  0.005f

// Output layout (fp32, concat): [0,4194304) z_q_st ; [4194304] vq_loss ;
// [4194305, 4259841) indices (as float)
//
// ws layout (bytes):
//   [0,131072)        ushort emb_hi[65536]     (dead after vq_scan)
//   [131072,262144)   ushort emb_lo[65536]     (dead after vq_scan)
//   [262144,266240)   float  enorm[1024]
//   [266240,266244)   int    risky_cnt
//   [131072,147456)   float  partials[4096]    (gather; overlaps dead emb_lo)
// risky list itself lives in d_out's z_q region (dead until vq_gather).

__device__ inline unsigned short bf16_rne(float f) {
    union { float fv; unsigned u; } a; a.fv = f;
    unsigned r = a.u + 0x7FFFu + ((a.u >> 16) & 1u);
    return (unsigned short)(r >> 16);
}
__device__ inline float bf16_to_f(unsigned short h) {
    union { unsigned u; float fv; } a; a.u = ((unsigned)h) << 16;
    return a.fv;
}

__global__ __launch_bounds__(256) void vq_prep(const float* __restrict__ emb,
        unsigned short* __restrict__ ehi, unsigned short* __restrict__ elo,
        float* __restrict__ enorm) {
    const int k = blockIdx.x * 256 + threadIdx.x;   // grid 4
    const float4* e4 = (const float4*)(emb + k * 64);
    float s = 0.f;
#pragma unroll
    for (int j = 0; j < 16; ++j) {
        float4 v = e4[j];
        float vv[4] = {v.x, v.y, v.z, v.w};
        ushort4 hv, lv;
        unsigned short h[4], l[4];
#pragma unroll
        for (int t = 0; t < 4; ++t) {
            s = fmaf(vv[t], vv[t], s);
            h[t] = bf16_rne(vv[t]);
            l[t] = bf16_rne(vv[t] - bf16_to_f(h[t]));
        }
        hv.x = h[0]; hv.y = h[1]; hv.z = h[2]; hv.w = h[3];
        lv.x = l[0]; lv.y = l[1]; lv.z = l[2]; lv.w = l[3];
        *(ushort4*)(ehi + k * 64 + j * 4) = hv;
        *(ushort4*)(elo + k * 64 + j * 4) = lv;
    }
    enorm[k] = s;
}

// Block 256 = 4 waves = 2 pixel-supergroups(64 pix) x 2 code-halves(512 codes).
#define LOADB(c, EH0, EH1, EL0, EL1, EN) {                    \
    const int code_ = chbase + (c) * 16 + col;                \
    const unsigned short* ph_ = ehi + code_ * 64 + g * 8;     \
    const unsigned short* pl_ = elo + code_ * 64 + g * 8;     \
    EH0 = *(const short8*)ph_;  EH1 = *(const short8*)(ph_ + 32); \
    EL0 = *(const short8*)pl_;  EL1 = *(const short8*)(pl_ + 32); \
    EN  = enorm[code_]; }

__global__ __launch_bounds__(256, 2) void vq_scan(const float* __restrict__ z_e,
        const unsigned short* __restrict__ ehi, const unsigned short* __restrict__ elo,
        const float* __restrict__ enorm, float* __restrict__ out) {
    const int lane = threadIdx.x & 63;
    const int col  = lane & 15;
    const int g    = lane >> 4;
    const int wv   = threadIdx.x >> 6;
    const int pg   = wv >> 1;
    const int ch   = wv & 1;
    const int pbase = blockIdx.x * 128 + pg * 64;
    const int chbase = ch * 512;

    short8 fh[4][2], fl[4][2];
#pragma unroll
    for (int q = 0; q < 4; ++q) {
        const int p = pbase + q * 16 + col;
        const float* zb = z_e + (p >> 12) * 262144 + (p & 4095);
#pragma unroll
        for (int j = 0; j < 8; ++j) {
            float v0 = zb[(g * 8 + j) * 4096];
            float v1 = zb[(32 + g * 8 + j) * 4096];
            unsigned short h0 = bf16_rne(v0);
            unsigned short h1 = bf16_rne(v1);
            fh[q][0][j] = (short)h0; fl[q][0][j] = (short)bf16_rne(v0 - bf16_to_f(h0));
            fh[q][1][j] = (short)h1; fl[q][1][j] = (short)bf16_rne(v1 - bf16_to_f(h1));
        }
    }

    float b1[4][4], b2[4][4]; int k1[4][4];
#pragma unroll
    for (int q = 0; q < 4; ++q)
#pragma unroll
        for (int r = 0; r < 4; ++r) { b1[q][r] = -INFINITY; b2[q][r] = -INFINITY; k1[q][r] = 0; }

    const f32x4 zero4 = {0.f, 0.f, 0.f, 0.f};
    short8 eh0a, eh1a, el0a, el1a; float ena;
    LOADB(0, eh0a, eh1a, el0a, el1a, ena);

#pragma unroll 2
    for (int c = 0; c < 32; ++c) {
        short8 eh0b, eh1b, el0b, el1b; float enb;
        LOADB((c + 1) & 31, eh0b, eh1b, el0b, el1b, enb);
        const int codecur = chbase + c * 16 + col;
#pragma unroll
        for (int q = 0; q < 4; ++q) {
            f32x4 acc;
            acc = __builtin_amdgcn_mfma_f32_16x16x32_bf16(fh[q][0], eh0a, zero4, 0, 0, 0);
            acc = __builtin_amdgcn_mfma_f32_16x16x32_bf16(fh[q][1], eh1a, acc, 0, 0, 0);
            acc = __builtin_amdgcn_mfma_f32_16x16x32_bf16(fl[q][0], eh0a, acc, 0, 0, 0);
            acc = __builtin_amdgcn_mfma_f32_16x16x32_bf16(fl[q][1], eh1a, acc, 0, 0, 0);
            acc = __builtin_amdgcn_mfma_f32_16x16x32_bf16(fh[q][0], el0a, acc, 0, 0, 0);
            acc = __builtin_amdgcn_mfma_f32_16x16x32_bf16(fh[q][1], el1a, acc, 0, 0, 0);
#pragma unroll
            for (int r = 0; r < 4; ++r) {
                float v = fmaf(ena, -0.5f, acc[r]);
                bool better = v > b1[q][r];
                b2[q][r] = better ? b1[q][r] : fmaxf(b2[q][r], v);
                k1[q][r] = better ? codecur : k1[q][r];
                b1[q][r] = fmaxf(b1[q][r], v);
            }
        }
        eh0a = eh0b; eh1a = eh1b; el0a = el0b; el1a = el1b; ena = enb;
    }

#pragma unroll
    for (int s = 1; s < 16; s <<= 1) {
#pragma unroll
        for (int q = 0; q < 4; ++q)
#pragma unroll
            for (int r = 0; r < 4; ++r) {
                float o1 = __shfl_xor(b1[q][r], s, 64);
                float o2 = __shfl_xor(b2[q][r], s, 64);
                int   oi = __shfl_xor(k1[q][r], s, 64);
                bool take = (o1 > b1[q][r]) || (o1 == b1[q][r] && oi < k1[q][r]);
                float nb2 = fmaxf(fminf(b1[q][r], o1), fmaxf(b2[q][r], o2));
                b1[q][r] = take ? o1 : b1[q][r];
                k1[q][r] = take ? oi : k1[q][r];
                b2[q][r] = nb2;
            }
    }

    __shared__ float sb1[2][64];
    __shared__ float sb2[2][64];
    __shared__ int   sk1[2][64];
    if (ch == 1 && col == 0) {
#pragma unroll
        for (int q = 0; q < 4; ++q)
#pragma unroll
            for (int r = 0; r < 4; ++r) {
                const int idx = g * 16 + q * 4 + r;
                sb1[pg][idx] = b1[q][r]; sb2[pg][idx] = b2[q][r]; sk1[pg][idx] = k1[q][r];
            }
    }
    __syncthreads();
    if (ch == 0 && col == 0) {
#pragma unroll
        for (int q = 0; q < 4; ++q)
#pragma unroll
            for (int r = 0; r < 4; ++r) {
                const int idx = g * 16 + q * 4 + r;
                float o1 = sb1[pg][idx], o2 = sb2[pg][idx]; int oi = sk1[pg][idx];
                float nb2 = fmaxf(fminf(b1[q][r], o1), fmaxf(b2[q][r], o2));
                if (o1 > b1[q][r]) { b1[q][r] = o1; k1[q][r] = oi; }
                b2[q][r] = nb2;
                const int pix = pbase + q * 16 + g * 4 + r;
                float flag = (b1[q][r] - b2[q][r] < EPS_HALF) ? RISK_FLAG : 0.0f;
                out[ZQ_ELEMS + 1 + pix] = (float)k1[q][r] + flag;
            }
    }
}

// Compact flagged pixels into a list (stored in d_out's dead z_q region). Grid 256.
__global__ __launch_bounds__(256) void vq_flag(const float* __restrict__ idxp,
        int* __restrict__ list, int* __restrict__ cnt) {
    const int pix = blockIdx.x * 256 + threadIdx.x;
    const int lane = threadIdx.x & 63;
    bool flagged = idxp[pix] >= RISK_FLAG;
    unsigned long long m = __ballot(flagged);
    int base = 0;
    int nwave = __popcll(m);
    if (lane == 0 && nwave) base = atomicAdd(cnt, nwave);
    base = __shfl(base, 0, 64);
    if (flagged) {
        int pos = base + __popcll(m & ((1ull << lane) - 1ull));
        list[pos] = pix;
    }
}

// Exact fp64 rescore: one wave per flagged item. Grid 256 (1024 waves).
__global__ __launch_bounds__(256) void vq_rescore(const float* __restrict__ z_e,
        const float* __restrict__ emb, float* __restrict__ out,
        const int* __restrict__ cnt, const int* __restrict__ list) {
    const int lane = threadIdx.x & 63;
    const int wid  = (blockIdx.x * 256 + threadIdx.x) >> 6;
    const int nw   = gridDim.x * 4;
    float* idxp = out + ZQ_ELEMS + 1;
    const int n = *cnt;
    for (int item = wid; item < n; item += nw) {
        const int pix = list[item];
        const float* zb = z_e + (pix >> 12) * 262144 + (pix & 4095);
        float f[64];
#pragma unroll
        for (int d = 0; d < 64; ++d) f[d] = zb[d * 4096];
        double best = INFINITY; int bk = KC;
        for (int j = 0; j < 16; ++j) {
            const int k = j * 64 + lane;
            const float* e = emb + k * 64;
            double a0 = 0.0, a1 = 0.0;
#pragma unroll
            for (int d = 0; d < 64; d += 2) {
                double d0 = (double)f[d]     - (double)e[d];
                double d1 = (double)f[d + 1] - (double)e[d + 1];
                a0 = fma(d0, d0, a0);
                a1 = fma(d1, d1, a1);
            }
            double acc = a0 + a1;
            if (acc < best || (acc == best && k < bk)) { best = acc; bk = k; }
        }
        for (int off = 32; off; off >>= 1) {
            double ov = __shfl_down(best, off, 64);
            int    oi = __shfl_down(bk, off, 64);
            if (ov < best || (ov == best && oi < bk)) { best = ov; bk = oi; }
        }
        if (lane == 0) idxp[pix] = (float)bk;
    }
}

// Dim-major gather: thread handles 4 consecutive elements of (B,D,H,W). Grid 4096.
__global__ __launch_bounds__(256) void vq_gather(
        const float* __restrict__ z_e, const float* __restrict__ emb,
        float* __restrict__ out, float* __restrict__ partials) {
    const int E = (blockIdx.x * 256 + threadIdx.x) * 4;
    const int b = E >> 18, d = (E >> 12) & 63, hw = E & 4095;
    const int pixbase = (b << 12) + hw;
    const float* idxp = out + ZQ_ELEMS + 1;
    float4 z = *(const float4*)(z_e + E);
    int k0 = (int)idxp[pixbase + 0];
    int k1 = (int)idxp[pixbase + 1];
    int k2 = (int)idxp[pixbase + 2];
    int k3 = (int)idxp[pixbase + 3];
    float4 q;
    q.x = emb[k0 * 64 + d]; q.y = emb[k1 * 64 + d];
    q.z = emb[k2 * 64 + d]; q.w = emb[k3 * 64 + d];
    *(float4*)(out + E) = q;
    float d0 = q.x - z.x, d1 = q.y - z.y, d2 = q.z - z.z, d3 = q.w - z.w;
    float ss = d0 * d0 + d1 * d1 + d2 * d2 + d3 * d3;
    for (int off = 32; off; off >>= 1) ss += __shfl_down(ss, off, 64);
    __shared__ float sred[4];
    if ((threadIdx.x & 63) == 0) sred[threadIdx.x >> 6] = ss;
    __syncthreads();
    if (threadIdx.x == 0)
        partials[blockIdx.x] = (sred[0] + sred[1]) + (sred[2] + sred[3]);
}

__global__ __launch_bounds__(256) void vq_finalize(const float* __restrict__ partials,
                                                   float* __restrict__ out) {
    float acc = 0.f;
#pragma unroll
    for (int i = 0; i < 16; ++i) acc += partials[threadIdx.x * 16 + i];
    for (int off = 32; off; off >>= 1) acc += __shfl_down(acc, off, 64);
    __shared__ float sred[4];
    if ((threadIdx.x & 63) == 0) sred[threadIdx.x >> 6] = acc;
    __syncthreads();
    if (threadIdx.x == 0)
        out[ZQ_ELEMS] = ((sred[0] + sred[1]) + (sred[2] + sred[3])) *
                        (1.25f / (float)ZQ_ELEMS);
}

extern "C" void kernel_launch(void* const* d_in, const int* in_sizes, int n_in,
                              void* d_out, int out_size, void* d_ws, size_t ws_size,
                              hipStream_t stream) {
    const float* z_e = (const float*)d_in[0];
    const float* emb = (const float*)d_in[1];
    float* out = (float*)d_out;
    char* ws = (char*)d_ws;
    unsigned short* ehi = (unsigned short*)ws;
    unsigned short* elo = (unsigned short*)(ws + 131072);
    float* enorm     = (float*)(ws + 262144);
    int*   risky_cnt = (int*)(ws + 266240);
    float* partials  = (float*)(ws + 131072);   // overlaps elo (dead by gather time)
    int*   risky     = (int*)out;               // z_q region, dead until vq_gather

    hipMemsetAsync(risky_cnt, 0, 4, stream);
    vq_prep<<<4, 256, 0, stream>>>(emb, ehi, elo, enorm);
    vq_scan<<<512, 256, 0, stream>>>(z_e, ehi, elo, enorm, out);
    vq_flag<<<256, 256, 0, stream>>>(out + ZQ_ELEMS + 1, risky, risky_cnt);
    vq_rescore<<<256, 256, 0, stream>>>(z_e, emb, out, risky_cnt, risky);
    vq_gather<<<4096, 256, 0, stream>>>(z_e, emb, out, partials);
    vq_finalize<<<1, 256, 0, stream>>>(partials, out);
}